// Round 10
// baseline (196.824 us; speedup 1.0000x reference)
//
#include <hip/hip_runtime.h>
#include <math.h>

#define N_NODES 100000
#define N_EDGES 1600000
#define NB 782              // ceil(N_NODES / 128) buckets, bucket = dst >> 7
#define NTILES 6250         // N_NODES / 16 (exact)
#define NPART 256           // partition blocks

typedef unsigned int uint;
typedef __attribute__((ext_vector_type(8))) short bf16x8;
typedef __attribute__((ext_vector_type(4))) float f32x4;

__device__ inline ushort f2bf(float f) {
    uint u = __float_as_uint(f);
    uint r = (u + 0x7fffu + ((u >> 16) & 1u)) >> 16;
    return (ushort)r;
}
__device__ inline uint pack2bf(float lo, float hi) {
    return (uint)f2bf(lo) | ((uint)f2bf(hi) << 16);
}

// ---------------- fused prologue: weight-frag prep (blocks 0-79) + cast x->bf16 ----------------
__global__ void misc_kernel(const float* __restrict__ W1l, const float* __restrict__ W1r,
                            const float* __restrict__ W2l, const float* __restrict__ W2r,
                            const float* __restrict__ W3l, const float* __restrict__ W3r,
                            ushort* __restrict__ wf,
                            const float* __restrict__ x, ushort* __restrict__ xb) {
    if (blockIdx.x < 80) {
        int idx = blockIdx.x * 256 + threadIdx.x;
        if (idx >= 20480) return;
        const float *Wl, *Wr;
        int base, KT;
        if (idx < 8192)       { base = 0;     Wl = W1l; Wr = W1r; KT = 128; }
        else if (idx < 16384) { base = 8192;  Wl = W2l; Wr = W2r; KT = 128; }
        else if (idx < 18432) { base = 16384; Wl = W3l; Wr = 0;   KT = 64; }
        else                  { base = 18432; Wl = W3r; Wr = 0;   KT = 64; }
        int r = idx - base;
        int f = r >> 9;
        int l = (r >> 3) & 63;
        int i = r & 7;
        int nks = KT >> 5;
        int nt = f / nks, ks = f - nt * nks;
        int k = ks * 32 + ((l >> 4) << 3) + i;
        int j = nt * 16 + (l & 15);
        float v = (k < 64) ? Wl[j * 64 + k] : Wr[j * 64 + (k - 64)];
        wf[idx] = f2bf(v);
    } else {
        const int n4 = N_NODES * 64 / 4;
        int i0 = (blockIdx.x - 80) * 256 + threadIdx.x;
        for (int i = i0; i < n4; i += 400 * 256) {
            float4 v = ((const float4*)x)[i];
            uint2 o;
            o.x = pack2bf(v.x, v.y);
            o.y = pack2bf(v.z, v.w);
            ((uint2*)xb)[i] = o;
        }
    }
}

// ---------------- bucket-level histogram -> hist2D[block][bucket] (no atomics, no memset) ----------------
__global__ void bucket_hist(const int* __restrict__ dst, int* __restrict__ hist2D, int nE) {
    __shared__ int hist[NB];
    const int PER = (N_EDGES + NPART - 1) / NPART;
    int e0 = blockIdx.x * PER;
    int e1 = min(e0 + PER, nE);
    for (int i = threadIdx.x; i < NB; i += 1024) hist[i] = 0;
    __syncthreads();
    for (int e = e0 + threadIdx.x; e < e1; e += 1024)
        atomicAdd(&hist[dst[e] >> 7], 1);
    __syncthreads();
    for (int i = threadIdx.x; i < NB; i += 1024)
        hist2D[blockIdx.x * NB + i] = hist[i];
}

// ---------------- scan: bucket totals -> bucketBase; per-block bases -> base2D ----------------
__global__ void scan_buckets(const int* __restrict__ hist2D, int* __restrict__ bucketBase,
                             int* __restrict__ base2D) {
    __shared__ int s[1024];
    int tid = threadIdx.x;
    int tot = 0;
    if (tid < NB)
        for (int b = 0; b < NPART; ++b) tot += hist2D[b * NB + tid];
    s[tid] = tot;
    __syncthreads();
    for (int off = 1; off < 1024; off <<= 1) {
        int t = (tid >= off) ? s[tid - off] : 0;
        __syncthreads();
        s[tid] += t;
        __syncthreads();
    }
    if (tid < NB) {
        int run = s[tid] - tot;     // exclusive scan = bucket base
        bucketBase[tid] = run;
        for (int b = 0; b < NPART; ++b) {
            base2D[b * NB + tid] = run;
            run += hist2D[b * NB + tid];
        }
    }
    if (tid == 0) bucketBase[NB] = s[NB - 1];
}

// ---------------- partition edges into bucket regions (single pass, precomputed bases) ----------------
__global__ void partition_kernel(const int* __restrict__ src, const int* __restrict__ dst,
                                 const int* __restrict__ base2D, int* __restrict__ part, int nE) {
    __shared__ int base[NB];
    __shared__ int rank[NB];
    const int PER = (N_EDGES + NPART - 1) / NPART;
    int e0 = blockIdx.x * PER;
    int e1 = min(e0 + PER, nE);
    for (int i = threadIdx.x; i < NB; i += 1024) {
        base[i] = base2D[blockIdx.x * NB + i];
        rank[i] = 0;
    }
    __syncthreads();
    for (int e = e0 + threadIdx.x; e < e1; e += 1024) {
        int d = dst[e];
        int bk = d >> 7;
        int r = atomicAdd(&rank[bk], 1);
        part[base[bk] + r] = src[e] | ((d & 127) << 20);
    }
}

// ---------------- bucket fill: per-dst counts, rowptr, invdeg, col scatter (512 thr) ----------------
__global__ void bucket_fill2(const int* __restrict__ bucketBase, const int* __restrict__ part,
                             int* __restrict__ col, int* __restrict__ rowptr,
                             float* __restrict__ invdeg, int n) {
    __shared__ int cnt[128];
    __shared__ int cnt2[128];
    __shared__ int exclS[128];
    __shared__ int s[128];
    int b = blockIdx.x;
    int d0 = b << 7;
    int dl = min(128, n - d0);
    int ebeg = bucketBase[b], eend = bucketBase[b + 1];
    if (threadIdx.x < 128) { cnt[threadIdx.x] = 0; cnt2[threadIdx.x] = 0; }
    __syncthreads();
    for (int i = ebeg + (int)threadIdx.x; i < eend; i += 512)
        atomicAdd(&cnt[part[i] >> 20], 1);
    __syncthreads();
    if (threadIdx.x < 128) s[threadIdx.x] = cnt[threadIdx.x];
    __syncthreads();
    for (int off = 1; off < 128; off <<= 1) {
        int t = 0;
        if (threadIdx.x < 128 && threadIdx.x >= (unsigned)off) t = s[threadIdx.x - off];
        __syncthreads();
        if (threadIdx.x < 128) s[threadIdx.x] += t;
        __syncthreads();
    }
    if ((int)threadIdx.x < dl) {
        int c = cnt[threadIdx.x];
        int ex = ebeg + s[threadIdx.x] - c;
        rowptr[d0 + threadIdx.x] = ex;
        invdeg[d0 + threadIdx.x] = 1.0f / fmaxf((float)c, 1.0f);
        exclS[threadIdx.x] = ex;
    }
    if (threadIdx.x == 0 && d0 + dl == n) rowptr[n] = eend;
    __syncthreads();
    for (int i = ebeg + (int)threadIdx.x; i < eend; i += 512) {
        int v = part[i];
        int doff = v >> 20;
        int pos = exclS[doff] + atomicAdd(&cnt2[doff], 1);
        col[pos] = v & 0xFFFFF;
    }
}

// ---------------- gather mean (64 bf16 feats): 8-lane group per node, 16B/lane ----------------
__global__ void gather_mean(const ushort* __restrict__ xb, const int* __restrict__ rowptr,
                            const int* __restrict__ col, const float* __restrict__ invdeg,
                            ushort* __restrict__ meanb, int n) {
    int tid = blockIdx.x * blockDim.x + threadIdx.x;
    int wid = tid >> 6;
    int lane = threadIdx.x & 63;
    int grp = lane >> 3;      // 0..7: node within wave
    int li = lane & 7;        // lane in group: feature slice
    int node = wid * 8 + grp;
    if (node >= n) return;
    int beg = rowptr[node];
    int end = rowptr[node + 1];
    int fb = li * 8;
    float a0 = 0.f, a1 = 0.f, a2 = 0.f, a3 = 0.f, a4 = 0.f, a5 = 0.f, a6 = 0.f, a7 = 0.f;
    for (int i = beg; i < end; i += 8) {
        int idx = i + li;
        int ci = (idx < end) ? col[idx] : 0;
        int cnt = end - i;
#pragma unroll
        for (int t = 0; t < 8; ++t) {
            if (t < cnt) {
                int s = __shfl(ci, grp * 8 + t, 64);
                uint4 w = *(const uint4*)(xb + (size_t)s * 64 + fb);
                a0 += __uint_as_float(w.x << 16);
                a1 += __uint_as_float(w.x & 0xffff0000u);
                a2 += __uint_as_float(w.y << 16);
                a3 += __uint_as_float(w.y & 0xffff0000u);
                a4 += __uint_as_float(w.z << 16);
                a5 += __uint_as_float(w.z & 0xffff0000u);
                a6 += __uint_as_float(w.w << 16);
                a7 += __uint_as_float(w.w & 0xffff0000u);
            }
        }
    }
    float id = invdeg[node];
    uint4 o;
    o.x = pack2bf(a0 * id, a1 * id);
    o.y = pack2bf(a2 * id, a3 * id);
    o.z = pack2bf(a4 * id, a5 * id);
    o.w = pack2bf(a6 * id, a7 * id);
    *(uint4*)(meanb + (size_t)node * 64 + fb) = o;
}

// ---------------- gather mean (32 bf16 feats): 4-lane group per node, 16B/lane ----------------
__global__ void gather_mean32(const ushort* __restrict__ gb, const int* __restrict__ rowptr,
                              const int* __restrict__ col, const float* __restrict__ invdeg,
                              ushort* __restrict__ mean32b, int n) {
    int tid = blockIdx.x * blockDim.x + threadIdx.x;
    int wid = tid >> 6;
    int lane = threadIdx.x & 63;
    int grp = lane >> 2;      // 0..15: node within wave
    int li = lane & 3;        // feature slice
    int node = wid * 16 + grp;
    if (node >= n) return;
    int beg = rowptr[node];
    int end = rowptr[node + 1];
    int fb = li * 8;
    float a0 = 0.f, a1 = 0.f, a2 = 0.f, a3 = 0.f, a4 = 0.f, a5 = 0.f, a6 = 0.f, a7 = 0.f;
    for (int i = beg; i < end; i += 4) {
        int idx = i + li;
        int ci = (idx < end) ? col[idx] : 0;
        int cnt = end - i;
#pragma unroll
        for (int t = 0; t < 4; ++t) {
            if (t < cnt) {
                int s = __shfl(ci, grp * 4 + t, 64);
                uint4 w = *(const uint4*)(gb + (size_t)s * 32 + fb);
                a0 += __uint_as_float(w.x << 16);
                a1 += __uint_as_float(w.x & 0xffff0000u);
                a2 += __uint_as_float(w.y << 16);
                a3 += __uint_as_float(w.y & 0xffff0000u);
                a4 += __uint_as_float(w.z << 16);
                a5 += __uint_as_float(w.z & 0xffff0000u);
                a6 += __uint_as_float(w.w << 16);
                a7 += __uint_as_float(w.w & 0xffff0000u);
            }
        }
    }
    float id = invdeg[node];
    uint4 o;
    o.x = pack2bf(a0 * id, a1 * id);
    o.y = pack2bf(a2 * id, a3 * id);
    o.z = pack2bf(a4 * id, a5 * id);
    o.w = pack2bf(a6 * id, a7 * id);
    *(uint4*)(mean32b + (size_t)node * 32 + fb) = o;
}

// ---------------- MFMA transform (layers 1,2): h = relu([mean|x] @ Wcomb + b) ----------------
__global__ void __launch_bounds__(256)
mfma_transform(const ushort* __restrict__ rootb, const ushort* __restrict__ meanb,
               const ushort* __restrict__ wfrag, const float* __restrict__ bias,
               ushort* __restrict__ outb, int ntiles) {
    int wave = threadIdx.x >> 6;
    int lane = threadIdx.x & 63;

    bf16x8 wf[4][4];
#pragma unroll
    for (int nt = 0; nt < 4; ++nt)
#pragma unroll
        for (int ks = 0; ks < 4; ++ks)
            wf[nt][ks] = *(const bf16x8*)(wfrag + (size_t)((nt * 4 + ks) * 64 + lane) * 8);

    float bl[4];
#pragma unroll
    for (int nt = 0; nt < 4; ++nt) bl[nt] = bias[nt * 16 + (lane & 15)];

    int arow = lane & 15;
    int koff = (lane >> 4) * 8;
    int crow = (lane >> 4) * 4;
    int nwaves = gridDim.x * 4;

    for (int tile = blockIdx.x * 4 + wave; tile < ntiles; tile += nwaves) {
        int n0 = tile * 16;
        const ushort* mrow = meanb + (size_t)(n0 + arow) * 64 + koff;
        const ushort* xrow = rootb + (size_t)(n0 + arow) * 64 + koff;
        bf16x8 a0 = *(const bf16x8*)(mrow);
        bf16x8 a1 = *(const bf16x8*)(mrow + 32);
        bf16x8 a2 = *(const bf16x8*)(xrow);
        bf16x8 a3 = *(const bf16x8*)(xrow + 32);
#pragma unroll
        for (int nt = 0; nt < 4; ++nt) {
            f32x4 c = {0.f, 0.f, 0.f, 0.f};
            c = __builtin_amdgcn_mfma_f32_16x16x32_bf16(a0, wf[nt][0], c, 0, 0, 0);
            c = __builtin_amdgcn_mfma_f32_16x16x32_bf16(a1, wf[nt][1], c, 0, 0, 0);
            c = __builtin_amdgcn_mfma_f32_16x16x32_bf16(a2, wf[nt][2], c, 0, 0, 0);
            c = __builtin_amdgcn_mfma_f32_16x16x32_bf16(a3, wf[nt][3], c, 0, 0, 0);
#pragma unroll
            for (int i = 0; i < 4; ++i) {
                float v = fmaxf(c[i] + bl[nt], 0.0f);
                outb[(size_t)(n0 + crow + i) * 64 + nt * 16 + (lane & 15)] = f2bf(v);
            }
        }
    }
}

// ---------------- MFMA pre-transform layer 3: g = h @ W3l.T (K=64, N=32) ----------------
__global__ void __launch_bounds__(256)
mfma_pretrans3(const ushort* __restrict__ hb, const ushort* __restrict__ wfrag,
               ushort* __restrict__ gb, int ntiles) {
    int wave = threadIdx.x >> 6;
    int lane = threadIdx.x & 63;

    bf16x8 wf[2][2];
#pragma unroll
    for (int nt = 0; nt < 2; ++nt)
#pragma unroll
        for (int ks = 0; ks < 2; ++ks)
            wf[nt][ks] = *(const bf16x8*)(wfrag + (size_t)((nt * 2 + ks) * 64 + lane) * 8);

    int arow = lane & 15;
    int koff = (lane >> 4) * 8;
    int crow = (lane >> 4) * 4;
    int nwaves = gridDim.x * 4;

    for (int tile = blockIdx.x * 4 + wave; tile < ntiles; tile += nwaves) {
        int n0 = tile * 16;
        const ushort* hrow = hb + (size_t)(n0 + arow) * 64 + koff;
        bf16x8 a0 = *(const bf16x8*)(hrow);
        bf16x8 a1 = *(const bf16x8*)(hrow + 32);
#pragma unroll
        for (int nt = 0; nt < 2; ++nt) {
            f32x4 c = {0.f, 0.f, 0.f, 0.f};
            c = __builtin_amdgcn_mfma_f32_16x16x32_bf16(a0, wf[nt][0], c, 0, 0, 0);
            c = __builtin_amdgcn_mfma_f32_16x16x32_bf16(a1, wf[nt][1], c, 0, 0, 0);
#pragma unroll
            for (int i = 0; i < 4; ++i)
                gb[(size_t)(n0 + crow + i) * 32 + nt * 16 + (lane & 15)] = f2bf(c[i]);
        }
    }
}

// ---------------- MFMA layer 3 + head ----------------
__global__ void __launch_bounds__(256)
mfma_t3(const ushort* __restrict__ hb, const ushort* __restrict__ mean32b,
        const ushort* __restrict__ wfrag, const float* __restrict__ b3,
        const float* __restrict__ Wreg, const float* __restrict__ breg,
        float* __restrict__ out, int ntiles) {
    int wave = threadIdx.x >> 6;
    int lane = threadIdx.x & 63;

    bf16x8 wf[2][2];
#pragma unroll
    for (int nt = 0; nt < 2; ++nt)
#pragma unroll
        for (int ks = 0; ks < 2; ++ks)
            wf[nt][ks] = *(const bf16x8*)(wfrag + (size_t)((nt * 2 + ks) * 64 + lane) * 8);

    float bl[2], wr[2];
#pragma unroll
    for (int nt = 0; nt < 2; ++nt) {
        bl[nt] = b3[nt * 16 + (lane & 15)];
        wr[nt] = Wreg[nt * 16 + (lane & 15)];
    }
    float br = breg[0];

    int arow = lane & 15;
    int koff = (lane >> 4) * 8;
    int crow = (lane >> 4) * 4;
    int nwaves = gridDim.x * 4;

    for (int tile = blockIdx.x * 4 + wave; tile < ntiles; tile += nwaves) {
        int n0 = tile * 16;
        const ushort* hrow = hb + (size_t)(n0 + arow) * 64 + koff;
        bf16x8 a0 = *(const bf16x8*)(hrow);
        bf16x8 a1 = *(const bf16x8*)(hrow + 32);
        float part0 = 0.f, part1 = 0.f, part2 = 0.f, part3 = 0.f;
#pragma unroll
        for (int nt = 0; nt < 2; ++nt) {
            f32x4 c = {0.f, 0.f, 0.f, 0.f};
            c = __builtin_amdgcn_mfma_f32_16x16x32_bf16(a0, wf[nt][0], c, 0, 0, 0);
            c = __builtin_amdgcn_mfma_f32_16x16x32_bf16(a1, wf[nt][1], c, 0, 0, 0);
#pragma unroll
            for (int i = 0; i < 4; ++i) {
                ushort mw = mean32b[(size_t)(n0 + crow + i) * 32 + nt * 16 + (lane & 15)];
                float m = __uint_as_float((uint)mw << 16);
                float v = fmaxf(c[i] + bl[nt] + m, 0.0f) * wr[nt];
                if (i == 0) part0 += v;
                else if (i == 1) part1 += v;
                else if (i == 2) part2 += v;
                else part3 += v;
            }
        }
#pragma unroll
        for (int s = 1; s < 16; s <<= 1) {
            part0 += __shfl_xor(part0, s, 64);
            part1 += __shfl_xor(part1, s, 64);
            part2 += __shfl_xor(part2, s, 64);
            part3 += __shfl_xor(part3, s, 64);
        }
        if ((lane & 15) == 0) {
            float4 o;
            o.x = part0 + br; o.y = part1 + br; o.z = part2 + br; o.w = part3 + br;
            *(float4*)(out + n0 + crow) = o;
        }
    }
}

extern "C" void kernel_launch(void* const* d_in, const int* in_sizes, int n_in,
                              void* d_out, int out_size, void* d_ws, size_t ws_size,
                              hipStream_t stream) {
    const float* x    = (const float*)d_in[0];
    const int*   ei   = (const int*)d_in[1];
    const float* W1l  = (const float*)d_in[2];
    const float* b1   = (const float*)d_in[3];
    const float* W1r  = (const float*)d_in[4];
    const float* W2l  = (const float*)d_in[5];
    const float* b2   = (const float*)d_in[6];
    const float* W2r  = (const float*)d_in[7];
    const float* W3l  = (const float*)d_in[8];
    const float* b3   = (const float*)d_in[9];
    const float* W3r  = (const float*)d_in[10];
    const float* Wreg = (const float*)d_in[11];
    const float* breg = (const float*)d_in[12];

    const int* src = ei;
    const int* dst = ei + N_EDGES;

    char* p = (char*)d_ws;
    auto alloc = [&](size_t bytes) {
        char* r = p;
        p += (bytes + 255) & ~(size_t)255;
        return r;
    };
    int*    hist2D    = (int*)alloc((size_t)NPART * NB * sizeof(int));   // 800KB
    int*    base2D    = (int*)alloc((size_t)NPART * NB * sizeof(int));   // 800KB
    int*    bucketBase= (int*)alloc((NB + 1) * sizeof(int));
    int*    rowptr    = (int*)alloc((N_NODES + 1) * sizeof(int));
    int*    col       = (int*)alloc((size_t)N_EDGES * sizeof(int));
    float*  invdeg    = (float*)alloc(N_NODES * sizeof(float));
    ushort* wfrag     = (ushort*)alloc(20480 * sizeof(ushort));
    // slot shared by part (6.4MB) then gb (6.4MB); lifetimes don't overlap
    char*   slot   = (char*)alloc((size_t)N_EDGES * sizeof(int));
    int*    part   = (int*)slot;
    ushort* gb     = (ushort*)slot;
    ushort* xb     = (ushort*)alloc((size_t)N_NODES * 64 * sizeof(ushort));
    ushort* meanb  = (ushort*)alloc((size_t)N_NODES * 64 * sizeof(ushort)); // also mean32b
    ushort* mean32b= meanb;
    ushort* hb     = (ushort*)alloc((size_t)N_NODES * 64 * sizeof(ushort));
    float*  out    = (float*)d_out;

    const int TB = 256;
    int g64Blocks    = (N_NODES * 8 + TB - 1) / TB;    // 8 lanes per node
    int g32Blocks    = (N_NODES * 4 + TB - 1) / TB;    // 4 lanes per node
    const int mfmaBlocks = 1563;   // 6252 waves, 1 tile each

    // ---- prologue (prep_wfrag + cast fused) + CSR build ----
    misc_kernel<<<480, 256, 0, stream>>>(W1l, W1r, W2l, W2r, W3l, W3r, wfrag, x, xb);
    bucket_hist<<<NPART, 1024, 0, stream>>>(dst, hist2D, N_EDGES);
    scan_buckets<<<1, 1024, 0, stream>>>(hist2D, bucketBase, base2D);
    partition_kernel<<<NPART, 1024, 0, stream>>>(src, dst, base2D, part, N_EDGES);
    bucket_fill2<<<NB, 512, 0, stream>>>(bucketBase, part, col, rowptr, invdeg, N_NODES);

    // ---- layer 1 ----
    gather_mean<<<g64Blocks, 256, 0, stream>>>(xb, rowptr, col, invdeg, meanb, N_NODES);
    mfma_transform<<<mfmaBlocks, 256, 0, stream>>>(xb, meanb, wfrag + 0, b1, hb, NTILES);

    // ---- layer 2 ----
    gather_mean<<<g64Blocks, 256, 0, stream>>>(hb, rowptr, col, invdeg, meanb, N_NODES);
    mfma_transform<<<mfmaBlocks, 256, 0, stream>>>(hb, meanb, wfrag + 8192, b2, hb, NTILES);

    // ---- layer 3: pre-transform, 32-wide gather, fused head ----
    mfma_pretrans3<<<mfmaBlocks, 256, 0, stream>>>(hb, wfrag + 16384, gb, NTILES);  // gb aliases part (dead)
    gather_mean32<<<g32Blocks, 256, 0, stream>>>(gb, rowptr, col, invdeg, mean32b, N_NODES);
    mfma_t3<<<mfmaBlocks, 256, 0, stream>>>(hb, mean32b, wfrag + 18432, b3, Wreg, breg, out, NTILES);
}

// Round 11
// 169.021 us; speedup vs baseline: 1.1645x; 1.1645x over previous
//
#include <hip/hip_runtime.h>
#include <math.h>

#define N_NODES 100000
#define N_EDGES 1600000
#define NB 782              // ceil(N_NODES / 128) buckets, bucket = dst >> 7
#define NTILES 6250         // N_NODES / 16 (exact)
#define NPART 256           // partition blocks

typedef unsigned int uint;
typedef __attribute__((ext_vector_type(8))) short bf16x8;
typedef __attribute__((ext_vector_type(4))) float f32x4;

__device__ inline ushort f2bf(float f) {
    uint u = __float_as_uint(f);
    uint r = (u + 0x7fffu + ((u >> 16) & 1u)) >> 16;
    return (ushort)r;
}
__device__ inline uint pack2bf(float lo, float hi) {
    return (uint)f2bf(lo) | ((uint)f2bf(hi) << 16);
}

// ---------------- fused prologue: weight-frag prep (blocks 0-79) + cast x->bf16 ----------------
__global__ void misc_kernel(const float* __restrict__ W1l, const float* __restrict__ W1r,
                            const float* __restrict__ W2l, const float* __restrict__ W2r,
                            const float* __restrict__ W3l, const float* __restrict__ W3r,
                            ushort* __restrict__ wf,
                            const float* __restrict__ x, ushort* __restrict__ xb) {
    if (blockIdx.x < 80) {
        int idx = blockIdx.x * 256 + threadIdx.x;
        if (idx >= 20480) return;
        const float *Wl, *Wr;
        int base, KT;
        if (idx < 8192)       { base = 0;     Wl = W1l; Wr = W1r; KT = 128; }
        else if (idx < 16384) { base = 8192;  Wl = W2l; Wr = W2r; KT = 128; }
        else if (idx < 18432) { base = 16384; Wl = W3l; Wr = 0;   KT = 64; }
        else                  { base = 18432; Wl = W3r; Wr = 0;   KT = 64; }
        int r = idx - base;
        int f = r >> 9;
        int l = (r >> 3) & 63;
        int i = r & 7;
        int nks = KT >> 5;
        int nt = f / nks, ks = f - nt * nks;
        int k = ks * 32 + ((l >> 4) << 3) + i;
        int j = nt * 16 + (l & 15);
        float v = (k < 64) ? Wl[j * 64 + k] : Wr[j * 64 + (k - 64)];
        wf[idx] = f2bf(v);
    } else {
        const int n4 = N_NODES * 64 / 4;
        int i0 = (blockIdx.x - 80) * 256 + threadIdx.x;
        for (int i = i0; i < n4; i += 400 * 256) {
            float4 v = ((const float4*)x)[i];
            uint2 o;
            o.x = pack2bf(v.x, v.y);
            o.y = pack2bf(v.z, v.w);
            ((uint2*)xb)[i] = o;
        }
    }
}

// ---------------- bucket-level histogram -> hist2D[block][bucket] ----------------
__global__ void bucket_hist(const int* __restrict__ dst, int* __restrict__ hist2D, int nE) {
    __shared__ int hist[NB];
    const int PER = (N_EDGES + NPART - 1) / NPART;
    int e0 = blockIdx.x * PER;
    int e1 = min(e0 + PER, nE);
    for (int i = threadIdx.x; i < NB; i += 1024) hist[i] = 0;
    __syncthreads();
    for (int e = e0 + threadIdx.x; e < e1; e += 1024)
        atomicAdd(&hist[dst[e] >> 7], 1);
    __syncthreads();
    for (int i = threadIdx.x; i < NB; i += 1024)
        hist2D[blockIdx.x * NB + i] = hist[i];
}

// ---------------- segmented scan 1: per-bucket column scan over partition blocks ----------------
// block i scans hist2D[*][i] (NPART values) -> colExcl[b][i] (exclusive), bucketTot[i]
__global__ void col_scan(const int* __restrict__ hist2D, int* __restrict__ colExcl,
                         int* __restrict__ bucketTot) {
    __shared__ int s[NPART];
    int i = blockIdx.x;
    int v = hist2D[threadIdx.x * NB + i];
    s[threadIdx.x] = v;
    __syncthreads();
    for (int off = 1; off < NPART; off <<= 1) {
        int t = (threadIdx.x >= (unsigned)off) ? s[threadIdx.x - off] : 0;
        __syncthreads();
        s[threadIdx.x] += t;
        __syncthreads();
    }
    colExcl[threadIdx.x * NB + i] = s[threadIdx.x] - v;
    if (threadIdx.x == NPART - 1) bucketTot[i] = s[NPART - 1];
}

// ---------------- segmented scan 2: exclusive scan of bucket totals -> bucketBase ----------------
__global__ void scan_tot(const int* __restrict__ bucketTot, int* __restrict__ bucketBase) {
    __shared__ int s[1024];
    int tid = threadIdx.x;
    int v = (tid < NB) ? bucketTot[tid] : 0;
    s[tid] = v;
    __syncthreads();
    for (int off = 1; off < 1024; off <<= 1) {
        int t = (tid >= off) ? s[tid - off] : 0;
        __syncthreads();
        s[tid] += t;
        __syncthreads();
    }
    if (tid < NB) bucketBase[tid] = s[tid] - v;
    if (tid == 0) bucketBase[NB] = s[NB - 1];
}

// ---------------- partition edges (single pass, precomputed per-block bases) ----------------
__global__ void partition_kernel(const int* __restrict__ src, const int* __restrict__ dst,
                                 const int* __restrict__ bucketBase, const int* __restrict__ colExcl,
                                 int* __restrict__ part, int nE) {
    __shared__ int base[NB];
    __shared__ int rank[NB];
    const int PER = (N_EDGES + NPART - 1) / NPART;
    int e0 = blockIdx.x * PER;
    int e1 = min(e0 + PER, nE);
    for (int i = threadIdx.x; i < NB; i += 1024) {
        base[i] = bucketBase[i] + colExcl[blockIdx.x * NB + i];
        rank[i] = 0;
    }
    __syncthreads();
    for (int e = e0 + threadIdx.x; e < e1; e += 1024) {
        int d = dst[e];
        int bk = d >> 7;
        int r = atomicAdd(&rank[bk], 1);
        part[base[bk] + r] = src[e] | ((d & 127) << 20);
    }
}

// ---------------- bucket fill: per-dst counts, rowptr, invdeg, col scatter (512 thr) ----------------
__global__ void bucket_fill2(const int* __restrict__ bucketBase, const int* __restrict__ part,
                             int* __restrict__ col, int* __restrict__ rowptr,
                             float* __restrict__ invdeg, int n) {
    __shared__ int cnt[128];
    __shared__ int cnt2[128];
    __shared__ int exclS[128];
    __shared__ int s[128];
    int b = blockIdx.x;
    int d0 = b << 7;
    int dl = min(128, n - d0);
    int ebeg = bucketBase[b], eend = bucketBase[b + 1];
    if (threadIdx.x < 128) { cnt[threadIdx.x] = 0; cnt2[threadIdx.x] = 0; }
    __syncthreads();
    for (int i = ebeg + (int)threadIdx.x; i < eend; i += 512)
        atomicAdd(&cnt[part[i] >> 20], 1);
    __syncthreads();
    if (threadIdx.x < 128) s[threadIdx.x] = cnt[threadIdx.x];
    __syncthreads();
    for (int off = 1; off < 128; off <<= 1) {
        int t = 0;
        if (threadIdx.x < 128 && threadIdx.x >= (unsigned)off) t = s[threadIdx.x - off];
        __syncthreads();
        if (threadIdx.x < 128) s[threadIdx.x] += t;
        __syncthreads();
    }
    if ((int)threadIdx.x < dl) {
        int c = cnt[threadIdx.x];
        int ex = ebeg + s[threadIdx.x] - c;
        rowptr[d0 + threadIdx.x] = ex;
        invdeg[d0 + threadIdx.x] = 1.0f / fmaxf((float)c, 1.0f);
        exclS[threadIdx.x] = ex;
    }
    if (threadIdx.x == 0 && d0 + dl == n) rowptr[n] = eend;
    __syncthreads();
    for (int i = ebeg + (int)threadIdx.x; i < eend; i += 512) {
        int v = part[i];
        int doff = v >> 20;
        int pos = exclS[doff] + atomicAdd(&cnt2[doff], 1);
        col[pos] = v & 0xFFFFF;
    }
}

// ---------------- gather mean (64 bf16 feats): 8-lane group per node, 16B/lane ----------------
__global__ void gather_mean(const ushort* __restrict__ xb, const int* __restrict__ rowptr,
                            const int* __restrict__ col, const float* __restrict__ invdeg,
                            ushort* __restrict__ meanb, int n) {
    int tid = blockIdx.x * blockDim.x + threadIdx.x;
    int wid = tid >> 6;
    int lane = threadIdx.x & 63;
    int grp = lane >> 3;      // 0..7: node within wave
    int li = lane & 7;        // lane in group: feature slice
    int node = wid * 8 + grp;
    if (node >= n) return;
    int beg = rowptr[node];
    int end = rowptr[node + 1];
    int fb = li * 8;
    float a0 = 0.f, a1 = 0.f, a2 = 0.f, a3 = 0.f, a4 = 0.f, a5 = 0.f, a6 = 0.f, a7 = 0.f;
    for (int i = beg; i < end; i += 8) {
        int idx = i + li;
        int ci = (idx < end) ? col[idx] : 0;
        int cnt = end - i;
#pragma unroll
        for (int t = 0; t < 8; ++t) {
            if (t < cnt) {
                int s = __shfl(ci, grp * 8 + t, 64);
                uint4 w = *(const uint4*)(xb + (size_t)s * 64 + fb);
                a0 += __uint_as_float(w.x << 16);
                a1 += __uint_as_float(w.x & 0xffff0000u);
                a2 += __uint_as_float(w.y << 16);
                a3 += __uint_as_float(w.y & 0xffff0000u);
                a4 += __uint_as_float(w.z << 16);
                a5 += __uint_as_float(w.z & 0xffff0000u);
                a6 += __uint_as_float(w.w << 16);
                a7 += __uint_as_float(w.w & 0xffff0000u);
            }
        }
    }
    float id = invdeg[node];
    uint4 o;
    o.x = pack2bf(a0 * id, a1 * id);
    o.y = pack2bf(a2 * id, a3 * id);
    o.z = pack2bf(a4 * id, a5 * id);
    o.w = pack2bf(a6 * id, a7 * id);
    *(uint4*)(meanb + (size_t)node * 64 + fb) = o;
}

// ---------------- gather mean (32 bf16 feats): 4-lane group per node, 16B/lane ----------------
__global__ void gather_mean32(const ushort* __restrict__ gb, const int* __restrict__ rowptr,
                              const int* __restrict__ col, const float* __restrict__ invdeg,
                              ushort* __restrict__ mean32b, int n) {
    int tid = blockIdx.x * blockDim.x + threadIdx.x;
    int wid = tid >> 6;
    int lane = threadIdx.x & 63;
    int grp = lane >> 2;      // 0..15: node within wave
    int li = lane & 3;        // feature slice
    int node = wid * 16 + grp;
    if (node >= n) return;
    int beg = rowptr[node];
    int end = rowptr[node + 1];
    int fb = li * 8;
    float a0 = 0.f, a1 = 0.f, a2 = 0.f, a3 = 0.f, a4 = 0.f, a5 = 0.f, a6 = 0.f, a7 = 0.f;
    for (int i = beg; i < end; i += 4) {
        int idx = i + li;
        int ci = (idx < end) ? col[idx] : 0;
        int cnt = end - i;
#pragma unroll
        for (int t = 0; t < 4; ++t) {
            if (t < cnt) {
                int s = __shfl(ci, grp * 4 + t, 64);
                uint4 w = *(const uint4*)(gb + (size_t)s * 32 + fb);
                a0 += __uint_as_float(w.x << 16);
                a1 += __uint_as_float(w.x & 0xffff0000u);
                a2 += __uint_as_float(w.y << 16);
                a3 += __uint_as_float(w.y & 0xffff0000u);
                a4 += __uint_as_float(w.z << 16);
                a5 += __uint_as_float(w.z & 0xffff0000u);
                a6 += __uint_as_float(w.w << 16);
                a7 += __uint_as_float(w.w & 0xffff0000u);
            }
        }
    }
    float id = invdeg[node];
    uint4 o;
    o.x = pack2bf(a0 * id, a1 * id);
    o.y = pack2bf(a2 * id, a3 * id);
    o.z = pack2bf(a4 * id, a5 * id);
    o.w = pack2bf(a6 * id, a7 * id);
    *(uint4*)(mean32b + (size_t)node * 32 + fb) = o;
}

// ---------------- MFMA transform (layers 1,2): h = relu([mean|x] @ Wcomb + b) ----------------
__global__ void __launch_bounds__(256)
mfma_transform(const ushort* __restrict__ rootb, const ushort* __restrict__ meanb,
               const ushort* __restrict__ wfrag, const float* __restrict__ bias,
               ushort* __restrict__ outb, int ntiles) {
    int wave = threadIdx.x >> 6;
    int lane = threadIdx.x & 63;

    bf16x8 wf[4][4];
#pragma unroll
    for (int nt = 0; nt < 4; ++nt)
#pragma unroll
        for (int ks = 0; ks < 4; ++ks)
            wf[nt][ks] = *(const bf16x8*)(wfrag + (size_t)((nt * 4 + ks) * 64 + lane) * 8);

    float bl[4];
#pragma unroll
    for (int nt = 0; nt < 4; ++nt) bl[nt] = bias[nt * 16 + (lane & 15)];

    int arow = lane & 15;
    int koff = (lane >> 4) * 8;
    int crow = (lane >> 4) * 4;
    int nwaves = gridDim.x * 4;

    for (int tile = blockIdx.x * 4 + wave; tile < ntiles; tile += nwaves) {
        int n0 = tile * 16;
        const ushort* mrow = meanb + (size_t)(n0 + arow) * 64 + koff;
        const ushort* xrow = rootb + (size_t)(n0 + arow) * 64 + koff;
        bf16x8 a0 = *(const bf16x8*)(mrow);
        bf16x8 a1 = *(const bf16x8*)(mrow + 32);
        bf16x8 a2 = *(const bf16x8*)(xrow);
        bf16x8 a3 = *(const bf16x8*)(xrow + 32);
#pragma unroll
        for (int nt = 0; nt < 4; ++nt) {
            f32x4 c = {0.f, 0.f, 0.f, 0.f};
            c = __builtin_amdgcn_mfma_f32_16x16x32_bf16(a0, wf[nt][0], c, 0, 0, 0);
            c = __builtin_amdgcn_mfma_f32_16x16x32_bf16(a1, wf[nt][1], c, 0, 0, 0);
            c = __builtin_amdgcn_mfma_f32_16x16x32_bf16(a2, wf[nt][2], c, 0, 0, 0);
            c = __builtin_amdgcn_mfma_f32_16x16x32_bf16(a3, wf[nt][3], c, 0, 0, 0);
#pragma unroll
            for (int i = 0; i < 4; ++i) {
                float v = fmaxf(c[i] + bl[nt], 0.0f);
                outb[(size_t)(n0 + crow + i) * 64 + nt * 16 + (lane & 15)] = f2bf(v);
            }
        }
    }
}

// ---------------- MFMA pre-transform layer 3: g = h @ W3l.T (K=64, N=32) ----------------
__global__ void __launch_bounds__(256)
mfma_pretrans3(const ushort* __restrict__ hb, const ushort* __restrict__ wfrag,
               ushort* __restrict__ gb, int ntiles) {
    int wave = threadIdx.x >> 6;
    int lane = threadIdx.x & 63;

    bf16x8 wf[2][2];
#pragma unroll
    for (int nt = 0; nt < 2; ++nt)
#pragma unroll
        for (int ks = 0; ks < 2; ++ks)
            wf[nt][ks] = *(const bf16x8*)(wfrag + (size_t)((nt * 2 + ks) * 64 + lane) * 8);

    int arow = lane & 15;
    int koff = (lane >> 4) * 8;
    int crow = (lane >> 4) * 4;
    int nwaves = gridDim.x * 4;

    for (int tile = blockIdx.x * 4 + wave; tile < ntiles; tile += nwaves) {
        int n0 = tile * 16;
        const ushort* hrow = hb + (size_t)(n0 + arow) * 64 + koff;
        bf16x8 a0 = *(const bf16x8*)(hrow);
        bf16x8 a1 = *(const bf16x8*)(hrow + 32);
#pragma unroll
        for (int nt = 0; nt < 2; ++nt) {
            f32x4 c = {0.f, 0.f, 0.f, 0.f};
            c = __builtin_amdgcn_mfma_f32_16x16x32_bf16(a0, wf[nt][0], c, 0, 0, 0);
            c = __builtin_amdgcn_mfma_f32_16x16x32_bf16(a1, wf[nt][1], c, 0, 0, 0);
#pragma unroll
            for (int i = 0; i < 4; ++i)
                gb[(size_t)(n0 + crow + i) * 32 + nt * 16 + (lane & 15)] = f2bf(c[i]);
        }
    }
}

// ---------------- MFMA layer 3 + head ----------------
__global__ void __launch_bounds__(256)
mfma_t3(const ushort* __restrict__ hb, const ushort* __restrict__ mean32b,
        const ushort* __restrict__ wfrag, const float* __restrict__ b3,
        const float* __restrict__ Wreg, const float* __restrict__ breg,
        float* __restrict__ out, int ntiles) {
    int wave = threadIdx.x >> 6;
    int lane = threadIdx.x & 63;

    bf16x8 wf[2][2];
#pragma unroll
    for (int nt = 0; nt < 2; ++nt)
#pragma unroll
        for (int ks = 0; ks < 2; ++ks)
            wf[nt][ks] = *(const bf16x8*)(wfrag + (size_t)((nt * 2 + ks) * 64 + lane) * 8);

    float bl[2], wr[2];
#pragma unroll
    for (int nt = 0; nt < 2; ++nt) {
        bl[nt] = b3[nt * 16 + (lane & 15)];
        wr[nt] = Wreg[nt * 16 + (lane & 15)];
    }
    float br = breg[0];

    int arow = lane & 15;
    int koff = (lane >> 4) * 8;
    int crow = (lane >> 4) * 4;
    int nwaves = gridDim.x * 4;

    for (int tile = blockIdx.x * 4 + wave; tile < ntiles; tile += nwaves) {
        int n0 = tile * 16;
        const ushort* hrow = hb + (size_t)(n0 + arow) * 64 + koff;
        bf16x8 a0 = *(const bf16x8*)(hrow);
        bf16x8 a1 = *(const bf16x8*)(hrow + 32);
        float part0 = 0.f, part1 = 0.f, part2 = 0.f, part3 = 0.f;
#pragma unroll
        for (int nt = 0; nt < 2; ++nt) {
            f32x4 c = {0.f, 0.f, 0.f, 0.f};
            c = __builtin_amdgcn_mfma_f32_16x16x32_bf16(a0, wf[nt][0], c, 0, 0, 0);
            c = __builtin_amdgcn_mfma_f32_16x16x32_bf16(a1, wf[nt][1], c, 0, 0, 0);
#pragma unroll
            for (int i = 0; i < 4; ++i) {
                ushort mw = mean32b[(size_t)(n0 + crow + i) * 32 + nt * 16 + (lane & 15)];
                float m = __uint_as_float((uint)mw << 16);
                float v = fmaxf(c[i] + bl[nt] + m, 0.0f) * wr[nt];
                if (i == 0) part0 += v;
                else if (i == 1) part1 += v;
                else if (i == 2) part2 += v;
                else part3 += v;
            }
        }
#pragma unroll
        for (int s = 1; s < 16; s <<= 1) {
            part0 += __shfl_xor(part0, s, 64);
            part1 += __shfl_xor(part1, s, 64);
            part2 += __shfl_xor(part2, s, 64);
            part3 += __shfl_xor(part3, s, 64);
        }
        if ((lane & 15) == 0) {
            float4 o;
            o.x = part0 + br; o.y = part1 + br; o.z = part2 + br; o.w = part3 + br;
            *(float4*)(out + n0 + crow) = o;
        }
    }
}

extern "C" void kernel_launch(void* const* d_in, const int* in_sizes, int n_in,
                              void* d_out, int out_size, void* d_ws, size_t ws_size,
                              hipStream_t stream) {
    const float* x    = (const float*)d_in[0];
    const int*   ei   = (const int*)d_in[1];
    const float* W1l  = (const float*)d_in[2];
    const float* b1   = (const float*)d_in[3];
    const float* W1r  = (const float*)d_in[4];
    const float* W2l  = (const float*)d_in[5];
    const float* b2   = (const float*)d_in[6];
    const float* W2r  = (const float*)d_in[7];
    const float* W3l  = (const float*)d_in[8];
    const float* b3   = (const float*)d_in[9];
    const float* W3r  = (const float*)d_in[10];
    const float* Wreg = (const float*)d_in[11];
    const float* breg = (const float*)d_in[12];

    const int* src = ei;
    const int* dst = ei + N_EDGES;

    char* p = (char*)d_ws;
    auto alloc = [&](size_t bytes) {
        char* r = p;
        p += (bytes + 255) & ~(size_t)255;
        return r;
    };
    int*    hist2D    = (int*)alloc((size_t)NPART * NB * sizeof(int));   // 800KB
    int*    colExcl   = (int*)alloc((size_t)NPART * NB * sizeof(int));   // 800KB
    int*    bucketTot = (int*)alloc(NB * sizeof(int));
    int*    bucketBase= (int*)alloc((NB + 1) * sizeof(int));
    int*    rowptr    = (int*)alloc((N_NODES + 1) * sizeof(int));
    int*    col       = (int*)alloc((size_t)N_EDGES * sizeof(int));
    float*  invdeg    = (float*)alloc(N_NODES * sizeof(float));
    ushort* wfrag     = (ushort*)alloc(20480 * sizeof(ushort));
    // slot shared by part (6.4MB) then gb (6.4MB); lifetimes don't overlap
    char*   slot   = (char*)alloc((size_t)N_EDGES * sizeof(int));
    int*    part   = (int*)slot;
    ushort* gb     = (ushort*)slot;
    ushort* xb     = (ushort*)alloc((size_t)N_NODES * 64 * sizeof(ushort));
    ushort* meanb  = (ushort*)alloc((size_t)N_NODES * 64 * sizeof(ushort)); // also mean32b
    ushort* mean32b= meanb;
    ushort* hb     = (ushort*)alloc((size_t)N_NODES * 64 * sizeof(ushort));
    float*  out    = (float*)d_out;

    const int TB = 256;
    int g64Blocks    = (N_NODES * 8 + TB - 1) / TB;    // 8 lanes per node
    int g32Blocks    = (N_NODES * 4 + TB - 1) / TB;    // 4 lanes per node
    const int mfmaBlocks = 512;   // 2048 waves, ~3 tiles each (proven round 6-9)

    // ---- prologue (prep_wfrag + cast fused) + CSR build ----
    misc_kernel<<<480, 256, 0, stream>>>(W1l, W1r, W2l, W2r, W3l, W3r, wfrag, x, xb);
    bucket_hist<<<NPART, 1024, 0, stream>>>(dst, hist2D, N_EDGES);
    col_scan<<<NB, NPART, 0, stream>>>(hist2D, colExcl, bucketTot);
    scan_tot<<<1, 1024, 0, stream>>>(bucketTot, bucketBase);
    partition_kernel<<<NPART, 1024, 0, stream>>>(src, dst, bucketBase, colExcl, part, N_EDGES);
    bucket_fill2<<<NB, 512, 0, stream>>>(bucketBase, part, col, rowptr, invdeg, N_NODES);

    // ---- layer 1 ----
    gather_mean<<<g64Blocks, 256, 0, stream>>>(xb, rowptr, col, invdeg, meanb, N_NODES);
    mfma_transform<<<mfmaBlocks, 256, 0, stream>>>(xb, meanb, wfrag + 0, b1, hb, NTILES);

    // ---- layer 2 ----
    gather_mean<<<g64Blocks, 256, 0, stream>>>(hb, rowptr, col, invdeg, meanb, N_NODES);
    mfma_transform<<<mfmaBlocks, 256, 0, stream>>>(hb, meanb, wfrag + 8192, b2, hb, NTILES);

    // ---- layer 3: pre-transform, 32-wide gather, fused head ----
    mfma_pretrans3<<<mfmaBlocks, 256, 0, stream>>>(hb, wfrag + 16384, gb, NTILES);  // gb aliases part (dead)
    gather_mean32<<<g32Blocks, 256, 0, stream>>>(gb, rowptr, col, invdeg, mean32b, N_NODES);
    mfma_t3<<<mfmaBlocks, 256, 0, stream>>>(hb, mean32b, wfrag + 18432, b3, Wreg, breg, out, NTILES);
}